// Round 5
// baseline (151.025 us; speedup 1.0000x reference)
//
#include <hip/hip_runtime.h>
#include <hip/hip_bf16.h>

// Deduced harness dtypes (r0-r3 evidence):
//   inputs:  float32   (r1: reading as bf16 -> NaN from garbage exponents)
//   output:  float32   (r3: bf16-packed writes read as f32 -> absmax 0.80,
//                       i.e. actual[k] ~= true[2k+1]; comparison itself is
//                       bf16-rounded, threshold 2.5e-2)
// Pipeline:
//   0. prep_emb: cast emb f32 -> bf16 [1024][1024] in ws
//   1. transpose_cast: W_s1 (1024x512), W_e1 (2048x512) f32 -> bf16 [d][k]
//   2. init_start: ws_start[1024] = b_s2 (f32 accumulator)
//   3. gemm_fused (z=0,1,2): emb_bf @ {W_s1,W_e1[:H],W_e1[H:]} via bf16 MFMA
//        z=0: relu(+b_s1)*w_s2 -> shfl reduce -> atomicAdd ws_start
//        z=1: A_mat = a (f32)    z=2: C_mat = c + b_e1 (f32)
//   4. pairwise: end[b,i,j] = sum_d relu(A[i,d]+C[j,d])*w_e2[d] + b_e2 (VALU)
//      + block(0,0,0) emits start_logits = ws_start (f32)

typedef float f32x4 __attribute__((ext_vector_type(4)));
typedef __bf16 bf16x8 __attribute__((ext_vector_type(8)));

static __device__ __forceinline__ unsigned short f2bf(float f) {
  unsigned int u = __builtin_bit_cast(unsigned int, f);
  u += 0x7FFFu + ((u >> 16) & 1u);  // RNE
  return (unsigned short)(u >> 16);
}

// ------------------------------------------------------------ emb f32->bf16
__global__ __launch_bounds__(256) void prep_emb(
    const float* __restrict__ in, unsigned short* __restrict__ out) {
  int i = (blockIdx.x * 256 + threadIdx.x) * 8;  // 1,048,576 total
  float4 v0 = *(const float4*)&in[i];
  float4 v1 = *(const float4*)&in[i + 4];
  ushort4 o0, o1;
  o0.x = f2bf(v0.x); o0.y = f2bf(v0.y); o0.z = f2bf(v0.z); o0.w = f2bf(v0.w);
  o1.x = f2bf(v1.x); o1.y = f2bf(v1.y); o1.z = f2bf(v1.z); o1.w = f2bf(v1.w);
  *(ushort4*)&out[i] = o0;
  *(ushort4*)&out[i + 4] = o1;
}

// --------------------------------------------- transpose + cast f32 -> bf16
__global__ __launch_bounds__(256) void transpose_cast(
    const float* __restrict__ in, unsigned short* __restrict__ out,
    int R, int C) {  // in[R][C] f32 -> out[C][R] bf16
  __shared__ float tile[32][33];
  int r0 = blockIdx.x * 32, c0 = blockIdx.y * 32;
  int t = threadIdx.x;
  int a = t >> 3, b4 = t & 7;
  float4 v = *(const float4*)&in[(size_t)(r0 + a) * C + c0 + b4 * 4];
  tile[a][b4 * 4 + 0] = v.x;
  tile[a][b4 * 4 + 1] = v.y;
  tile[a][b4 * 4 + 2] = v.z;
  tile[a][b4 * 4 + 3] = v.w;
  __syncthreads();
  ushort4 o;
  o.x = f2bf(tile[b4 * 4 + 0][a]);
  o.y = f2bf(tile[b4 * 4 + 1][a]);
  o.z = f2bf(tile[b4 * 4 + 2][a]);
  o.w = f2bf(tile[b4 * 4 + 3][a]);
  *(ushort4*)&out[(size_t)(c0 + a) * R + r0 + b4 * 4] = o;
}

// --------------------------------------------------------------- init start
__global__ void init_start(float* __restrict__ ws_start,
                           const float* __restrict__ b_s2) {
  int i = blockIdx.x * blockDim.x + threadIdx.x;
  if (i < 1024) ws_start[i] = b_s2[0];
}

// --------------------------------------------------------------------- GEMM
// M=1024 (B*N), K=1024 (H), N=512 (HD). 128x128 tile, 4 waves (2x2 of 64x64),
// 16x16x32 bf16 MFMA.
__global__ __launch_bounds__(256) void gemm_fused(
    const unsigned short* __restrict__ Aemb,   // [1024][1024] bf16
    const unsigned short* __restrict__ Wt_s,   // [512][1024] bf16 (W_s1^T)
    const unsigned short* __restrict__ Wt_e,   // [512][2048] bf16 (W_e1^T)
    const float* __restrict__ b_s1,
    const float* __restrict__ w_s2,
    const float* __restrict__ b_e1,
    float* __restrict__ ws_start,
    float* __restrict__ A_mat,                 // [1024][512] f32
    float* __restrict__ C_mat) {               // [1024][512] f32 (c + b_e1)
  __shared__ unsigned short Al[128][40];
  __shared__ unsigned short Bl[128][40];
  int z = blockIdx.z;
  int n0 = blockIdx.x * 128;
  int m0 = blockIdx.y * 128;
  const unsigned short* Bmat = (z == 0) ? Wt_s : Wt_e;
  int bstride = (z == 0) ? 1024 : 2048;
  int bofs = (z == 2) ? 1024 : 0;

  int t = threadIdx.x;
  int lane = t & 63, wave = t >> 6;
  int wm = (wave >> 1) * 64, wn = (wave & 1) * 64;
  int lm = lane & 15, g = lane >> 4;

  f32x4 acc[4][4];
#pragma unroll
  for (int mi = 0; mi < 4; ++mi)
#pragma unroll
    for (int ni = 0; ni < 4; ++ni) acc[mi][ni] = (f32x4){0.f, 0.f, 0.f, 0.f};

  int sc = t & 3, sr = t >> 2;
  for (int k0 = 0; k0 < 1024; k0 += 32) {
    __syncthreads();
#pragma unroll
    for (int p = 0; p < 2; ++p) {
      int rr = sr + p * 64;
      *(uint4*)&Al[rr][sc * 8] =
          *(const uint4*)&Aemb[(size_t)(m0 + rr) * 1024 + k0 + sc * 8];
      *(uint4*)&Bl[rr][sc * 8] =
          *(const uint4*)&Bmat[(size_t)(n0 + rr) * bstride + bofs + k0 + sc * 8];
    }
    __syncthreads();
    bf16x8 af[4], bfr[4];
#pragma unroll
    for (int mi = 0; mi < 4; ++mi)
      af[mi] = *(const bf16x8*)&Al[wm + mi * 16 + lm][g * 8];
#pragma unroll
    for (int ni = 0; ni < 4; ++ni)
      bfr[ni] = *(const bf16x8*)&Bl[wn + ni * 16 + lm][g * 8];
#pragma unroll
    for (int mi = 0; mi < 4; ++mi)
#pragma unroll
      for (int ni = 0; ni < 4; ++ni)
        acc[mi][ni] = __builtin_amdgcn_mfma_f32_16x16x32_bf16(
            af[mi], bfr[ni], acc[mi][ni], 0, 0, 0);
  }

  if (z == 0) {
    float bs[4], wsv[4];
#pragma unroll
    for (int ni = 0; ni < 4; ++ni) {
      int col = n0 + wn + ni * 16 + lm;
      bs[ni] = b_s1[col];
      wsv[ni] = w_s2[col];
    }
#pragma unroll
    for (int mi = 0; mi < 4; ++mi) {
#pragma unroll
      for (int r = 0; r < 4; ++r) {
        float s = 0.f;
#pragma unroll
        for (int ni = 0; ni < 4; ++ni) {
          float v = acc[mi][ni][r] + bs[ni];
          v = fmaxf(v, 0.f);
          s += v * wsv[ni];
        }
        s += __shfl_xor(s, 1);
        s += __shfl_xor(s, 2);
        s += __shfl_xor(s, 4);
        s += __shfl_xor(s, 8);
        if (lm == 0) {
          int row = m0 + wm + mi * 16 + g * 4 + r;
          atomicAdd(&ws_start[row], s);
        }
      }
    }
  } else {
    float* Out = (z == 1) ? A_mat : C_mat;
    float badd[4];
#pragma unroll
    for (int ni = 0; ni < 4; ++ni) {
      int col = n0 + wn + ni * 16 + lm;
      badd[ni] = (z == 2) ? b_e1[col] : 0.f;
    }
#pragma unroll
    for (int mi = 0; mi < 4; ++mi)
#pragma unroll
      for (int ni = 0; ni < 4; ++ni) {
        int col = n0 + wn + ni * 16 + lm;
#pragma unroll
        for (int r = 0; r < 4; ++r) {
          int row = m0 + wm + mi * 16 + g * 4 + r;
          Out[(size_t)row * 512 + col] = acc[mi][ni][r] + badd[ni];
        }
      }
  }
}

// ----------------------------------------------------------------- pairwise
__global__ __launch_bounds__(256) void pairwise(
    const float* __restrict__ A_mat, const float* __restrict__ C_mat,
    const float* __restrict__ w_e2, const float* __restrict__ b_e2,
    const float* __restrict__ ws_start, float* __restrict__ out) {
  __shared__ float As[32][65];
  __shared__ float Cs[64][65];
  __shared__ float wl[512];
  int t = threadIdx.x;
  int b = blockIdx.z;
  int i0 = blockIdx.y * 32, j0 = blockIdx.x * 64;

  if (blockIdx.x == 0 && blockIdx.y == 0 && b == 0) {
    for (int i = t; i < 1024; i += 256) out[i] = ws_start[i];
  }
  for (int i = t; i < 512; i += 256) wl[i] = w_e2[i];
  float be2 = b_e2[0];

  int ti = t & 7, tj = t >> 3;
  float accv[4][2] = {{0.f, 0.f}, {0.f, 0.f}, {0.f, 0.f}, {0.f, 0.f}};
  const float* Abase = A_mat + (size_t)(b * 512 + i0) * 512;
  const float* Cbase = C_mat + (size_t)(b * 512 + j0) * 512;

  for (int dc = 0; dc < 512; dc += 64) {
    __syncthreads();
    for (int idx = t; idx < 32 * 16; idx += 256) {
      int r = idx >> 4, c4 = (idx & 15) * 4;
      float4 v = *(const float4*)&Abase[r * 512 + dc + c4];
      As[r][c4 + 0] = v.x; As[r][c4 + 1] = v.y;
      As[r][c4 + 2] = v.z; As[r][c4 + 3] = v.w;
    }
    for (int idx = t; idx < 64 * 16; idx += 256) {
      int r = idx >> 4, c4 = (idx & 15) * 4;
      float4 v = *(const float4*)&Cbase[r * 512 + dc + c4];
      Cs[r][c4 + 0] = v.x; Cs[r][c4 + 1] = v.y;
      Cs[r][c4 + 2] = v.z; Cs[r][c4 + 3] = v.w;
    }
    __syncthreads();
#pragma unroll 4
    for (int d = 0; d < 64; ++d) {
      float w = wl[dc + d];
      float a0 = As[ti * 4 + 0][d];
      float a1 = As[ti * 4 + 1][d];
      float a2 = As[ti * 4 + 2][d];
      float a3 = As[ti * 4 + 3][d];
      float c0 = Cs[tj * 2 + 0][d];
      float c1 = Cs[tj * 2 + 1][d];
      accv[0][0] += fmaxf(a0 + c0, 0.f) * w;
      accv[0][1] += fmaxf(a0 + c1, 0.f) * w;
      accv[1][0] += fmaxf(a1 + c0, 0.f) * w;
      accv[1][1] += fmaxf(a1 + c1, 0.f) * w;
      accv[2][0] += fmaxf(a2 + c0, 0.f) * w;
      accv[2][1] += fmaxf(a2 + c1, 0.f) * w;
      accv[3][0] += fmaxf(a3 + c0, 0.f) * w;
      accv[3][1] += fmaxf(a3 + c1, 0.f) * w;
    }
  }

  float* oe = out + 1024;
#pragma unroll
  for (int q = 0; q < 4; ++q) {
    int i = i0 + ti * 4 + q;
    float2 vv;
    vv.x = accv[q][0] + be2;
    vv.y = accv[q][1] + be2;
    *(float2*)&oe[(size_t)(b * 512 + i) * 512 + j0 + tj * 2] = vv;
  }
}

// -------------------------------------------------------------------- launch
extern "C" void kernel_launch(void* const* d_in, const int* in_sizes, int n_in,
                              void* d_out, int out_size, void* d_ws,
                              size_t ws_size, hipStream_t stream) {
  const float* emb  = (const float*)d_in[0];
  const float* W_s1 = (const float*)d_in[1];
  const float* b_s1 = (const float*)d_in[2];
  const float* w_s2 = (const float*)d_in[3];
  const float* b_s2 = (const float*)d_in[4];
  const float* W_e1 = (const float*)d_in[5];
  const float* b_e1 = (const float*)d_in[6];
  const float* w_e2 = (const float*)d_in[7];
  const float* b_e2 = (const float*)d_in[8];
  float* out = (float*)d_out;

  char* ws = (char*)d_ws;
  unsigned short* emb_bf = (unsigned short*)(ws);                  // 2 MB
  unsigned short* Wt_s = (unsigned short*)(ws + 2u * (1u << 20));  // 1 MB
  unsigned short* Wt_e = (unsigned short*)(ws + 3u * (1u << 20));  // 2 MB
  float* A_mat = (float*)(ws + 5u * (1u << 20));                   // 2 MB
  float* C_mat = (float*)(ws + 7u * (1u << 20));                   // 2 MB
  float* ws_start = (float*)(ws + 9u * (1u << 20));                // 4 KB

  hipLaunchKernelGGL(prep_emb, dim3(512), dim3(256), 0, stream, emb, emb_bf);
  hipLaunchKernelGGL(transpose_cast, dim3(32, 16), dim3(256), 0, stream,
                     W_s1, Wt_s, 1024, 512);
  hipLaunchKernelGGL(transpose_cast, dim3(64, 16), dim3(256), 0, stream,
                     W_e1, Wt_e, 2048, 512);
  hipLaunchKernelGGL(init_start, dim3(4), dim3(256), 0, stream, ws_start, b_s2);
  hipLaunchKernelGGL(gemm_fused, dim3(4, 8, 3), dim3(256), 0, stream,
                     emb_bf, Wt_s, Wt_e, b_s1, w_s2, b_e1, ws_start, A_mat,
                     C_mat);
  hipLaunchKernelGGL(pairwise, dim3(8, 16, 2), dim3(256), 0, stream,
                     A_mat, C_mat, w_e2, b_e2, ws_start, out);
}

// Round 6
// 129.276 us; speedup vs baseline: 1.1682x; 1.1682x over previous
//
#include <hip/hip_runtime.h>
#include <hip/hip_bf16.h>

// Harness dtypes (verified r5): inputs f32, output f32, tol 2.5e-2 (bf16-cmp).
// r5 counters: pairwise 47.8us @ 10% occupancy (256 blocks = 1/CU), VALUBusy 34%.
// This round: pairwise 32x32 tiles (512 blocks, d-major LDS -> 3 LDS reads per
// 12 VALU), gemm 64x64 tiles (384 blocks, K-step 64), fewer launches.
// Pipeline:
//   0. prep_emb: emb f32 -> bf16 [1024][1024]
//   1. transpose_cast2 (z=0/1): W_s1, W_e1 f32 -> bf16 [d][k]
//   2. init_start_out: out[0:1024] = b_s2
//   3. gemm_fused (z=0,1,2): bf16 MFMA; z=0 epilogue atomicAdds into out[0:1024]
//        z=1: A_mat = a (f32)   z=2: C_mat = c + b_e1 (f32)
//   4. pairwise: out[1024+ b*512*512 + i*512 + j] =
//        sum_d relu(A[i,d]+C[j,d])*w_e2[d] + b_e2   (plain stores)

typedef float f32x4 __attribute__((ext_vector_type(4)));
typedef __bf16 bf16x8 __attribute__((ext_vector_type(8)));

static __device__ __forceinline__ unsigned short f2bf(float f) {
  unsigned int u = __builtin_bit_cast(unsigned int, f);
  u += 0x7FFFu + ((u >> 16) & 1u);  // RNE
  return (unsigned short)(u >> 16);
}

// ------------------------------------------------------------ emb f32->bf16
__global__ __launch_bounds__(256) void prep_emb(
    const float* __restrict__ in, unsigned short* __restrict__ out) {
  int i = (blockIdx.x * 256 + threadIdx.x) * 8;  // 1,048,576 total
  float4 v0 = *(const float4*)&in[i];
  float4 v1 = *(const float4*)&in[i + 4];
  ushort4 o0, o1;
  o0.x = f2bf(v0.x); o0.y = f2bf(v0.y); o0.z = f2bf(v0.z); o0.w = f2bf(v0.w);
  o1.x = f2bf(v1.x); o1.y = f2bf(v1.y); o1.z = f2bf(v1.z); o1.w = f2bf(v1.w);
  *(ushort4*)&out[i] = o0;
  *(ushort4*)&out[i + 4] = o1;
}

// ------------------------------- both weight transposes in one launch (z sel)
__global__ __launch_bounds__(256) void transpose_cast2(
    const float* __restrict__ W_s1, const float* __restrict__ W_e1,
    unsigned short* __restrict__ Wt_s, unsigned short* __restrict__ Wt_e) {
  int z = blockIdx.z;
  if (z == 0 && blockIdx.x >= 32) return;  // W_s1 has only 32 row-tiles
  const float* in = z ? W_e1 : W_s1;
  unsigned short* out = z ? Wt_e : Wt_s;
  int R = z ? 2048 : 1024;
  const int C = 512;
  __shared__ float tile[32][33];
  int r0 = blockIdx.x * 32, c0 = blockIdx.y * 32;
  int t = threadIdx.x;
  int a = t >> 3, b4 = t & 7;
  float4 v = *(const float4*)&in[(size_t)(r0 + a) * C + c0 + b4 * 4];
  tile[a][b4 * 4 + 0] = v.x;
  tile[a][b4 * 4 + 1] = v.y;
  tile[a][b4 * 4 + 2] = v.z;
  tile[a][b4 * 4 + 3] = v.w;
  __syncthreads();
  ushort4 o;
  o.x = f2bf(tile[b4 * 4 + 0][a]);
  o.y = f2bf(tile[b4 * 4 + 1][a]);
  o.z = f2bf(tile[b4 * 4 + 2][a]);
  o.w = f2bf(tile[b4 * 4 + 3][a]);
  *(ushort4*)&out[(size_t)(c0 + a) * R + r0 + b4 * 4] = o;
}

// ------------------------------------------------- out[0:1024] = b_s2 (f32)
__global__ void init_start_out(float* __restrict__ out,
                               const float* __restrict__ b_s2) {
  float v = b_s2[0];
  int i = threadIdx.x * 4;
  float4 o = {v, v, v, v};
  *(float4*)&out[i] = o;  // 256 threads x 4 = 1024
}

// --------------------------------------------------------------------- GEMM
// M=1024, K=1024, N=512 (x3 weight slices via z). 64x64 tile, K-step 64,
// 4 waves (2x2 of 32x32), 16x16x32 bf16 MFMA. Grid (8,16,3) = 384 blocks.
__global__ __launch_bounds__(256) void gemm_fused(
    const unsigned short* __restrict__ Aemb,   // [1024][1024] bf16
    const unsigned short* __restrict__ Wt_s,   // [512][1024] bf16 (W_s1^T)
    const unsigned short* __restrict__ Wt_e,   // [512][2048] bf16 (W_e1^T)
    const float* __restrict__ b_s1,
    const float* __restrict__ w_s2,
    const float* __restrict__ b_e1,
    float* __restrict__ out,                   // start logits at [0:1024]
    float* __restrict__ A_mat,                 // [1024][512] f32
    float* __restrict__ C_mat) {               // [1024][512] f32 (c + b_e1)
  __shared__ unsigned short Al[64][72];  // K-step 64, pad to 72 (16B rows)
  __shared__ unsigned short Bl[64][72];
  int z = blockIdx.z;
  int n0 = blockIdx.x * 64;
  int m0 = blockIdx.y * 64;
  const unsigned short* Bmat = (z == 0) ? Wt_s : Wt_e;
  int bstride = (z == 0) ? 1024 : 2048;
  int bofs = (z == 2) ? 1024 : 0;

  int t = threadIdx.x;
  int lane = t & 63, wave = t >> 6;
  int wm = (wave >> 1) * 32, wn = (wave & 1) * 32;
  int lm = lane & 15, g = lane >> 4;

  f32x4 acc[2][2];
#pragma unroll
  for (int mi = 0; mi < 2; ++mi)
#pragma unroll
    for (int ni = 0; ni < 2; ++ni) acc[mi][ni] = (f32x4){0.f, 0.f, 0.f, 0.f};

  int srow = t >> 2, sc = (t & 3) * 16;
  for (int k0 = 0; k0 < 1024; k0 += 64) {
    __syncthreads();
    const unsigned short* ap = &Aemb[(size_t)(m0 + srow) * 1024 + k0 + sc];
    const unsigned short* bp =
        &Bmat[(size_t)(n0 + srow) * bstride + bofs + k0 + sc];
    *(uint4*)&Al[srow][sc] = *(const uint4*)ap;
    *(uint4*)&Al[srow][sc + 8] = *(const uint4*)(ap + 8);
    *(uint4*)&Bl[srow][sc] = *(const uint4*)bp;
    *(uint4*)&Bl[srow][sc + 8] = *(const uint4*)(bp + 8);
    __syncthreads();
#pragma unroll
    for (int kk = 0; kk < 2; ++kk) {
      bf16x8 af[2], bfr[2];
#pragma unroll
      for (int mi = 0; mi < 2; ++mi)
        af[mi] = *(const bf16x8*)&Al[wm + mi * 16 + lm][kk * 32 + g * 8];
#pragma unroll
      for (int ni = 0; ni < 2; ++ni)
        bfr[ni] = *(const bf16x8*)&Bl[wn + ni * 16 + lm][kk * 32 + g * 8];
#pragma unroll
      for (int mi = 0; mi < 2; ++mi)
#pragma unroll
        for (int ni = 0; ni < 2; ++ni)
          acc[mi][ni] = __builtin_amdgcn_mfma_f32_16x16x32_bf16(
              af[mi], bfr[ni], acc[mi][ni], 0, 0, 0);
    }
  }

  if (z == 0) {
    float bs[2], wsv[2];
#pragma unroll
    for (int ni = 0; ni < 2; ++ni) {
      int col = n0 + wn + ni * 16 + lm;
      bs[ni] = b_s1[col];
      wsv[ni] = w_s2[col];
    }
#pragma unroll
    for (int mi = 0; mi < 2; ++mi) {
#pragma unroll
      for (int r = 0; r < 4; ++r) {
        float s = 0.f;
#pragma unroll
        for (int ni = 0; ni < 2; ++ni) {
          float v = acc[mi][ni][r] + bs[ni];
          v = fmaxf(v, 0.f);
          s += v * wsv[ni];
        }
        s += __shfl_xor(s, 1);
        s += __shfl_xor(s, 2);
        s += __shfl_xor(s, 4);
        s += __shfl_xor(s, 8);
        if (lm == 0) {
          int row = m0 + wm + mi * 16 + g * 4 + r;
          atomicAdd(&out[row], s);
        }
      }
    }
  } else {
    float* Out = (z == 1) ? A_mat : C_mat;
    float badd[2];
#pragma unroll
    for (int ni = 0; ni < 2; ++ni) {
      int col = n0 + wn + ni * 16 + lm;
      badd[ni] = (z == 2) ? b_e1[col] : 0.f;
    }
#pragma unroll
    for (int mi = 0; mi < 2; ++mi)
#pragma unroll
      for (int ni = 0; ni < 2; ++ni) {
        int col = n0 + wn + ni * 16 + lm;
#pragma unroll
        for (int r = 0; r < 4; ++r) {
          int row = m0 + wm + mi * 16 + g * 4 + r;
          Out[(size_t)row * 512 + col] = acc[mi][ni][r] + badd[ni];
        }
      }
  }
}

// ----------------------------------------------------------------- pairwise
// 32x32 output tile per block, grid (16,16,2) = 512 blocks (2/CU).
// LDS holds tiles d-major (As_t[d][i]) so per-d reads are vector b64 +
// broadcast: 3 LDS reads per 12 VALU ops.
__global__ __launch_bounds__(256) void pairwise(
    const float* __restrict__ A_mat, const float* __restrict__ C_mat,
    const float* __restrict__ w_e2, const float* __restrict__ b_e2,
    float* __restrict__ out) {
  __shared__ float As_t[64][36];  // [d][i], pad 36: rows 144B (16B-aligned)
  __shared__ float Cs_t[64][36];  // [d][j]
  __shared__ float wl[512];
  int t = threadIdx.x;
  int b = blockIdx.z;
  int j0 = blockIdx.x * 32, i0 = blockIdx.y * 32;

  for (int i = t; i < 512; i += 256) wl[i] = w_e2[i];
  float be2 = b_e2[0];

  int ti = t & 15, tj = t >> 4;  // 16x2 i-rows, 16x2 j-cols
  float accv[2][2] = {{0.f, 0.f}, {0.f, 0.f}};
  const float* Abase = A_mat + (size_t)(b * 512 + i0) * 512;
  const float* Cbase = C_mat + (size_t)(b * 512 + j0) * 512;

  int si = t & 31, sq = t >> 5;  // stage: row si, d-quad sq (0..7)
  for (int dc = 0; dc < 512; dc += 64) {
    __syncthreads();
#pragma unroll
    for (int p = 0; p < 2; ++p) {
      int d0 = sq * 4 + p * 32;
      float4 va = *(const float4*)&Abase[(size_t)si * 512 + dc + d0];
      As_t[d0 + 0][si] = va.x;
      As_t[d0 + 1][si] = va.y;
      As_t[d0 + 2][si] = va.z;
      As_t[d0 + 3][si] = va.w;
      float4 vc = *(const float4*)&Cbase[(size_t)si * 512 + dc + d0];
      Cs_t[d0 + 0][si] = vc.x;
      Cs_t[d0 + 1][si] = vc.y;
      Cs_t[d0 + 2][si] = vc.z;
      Cs_t[d0 + 3][si] = vc.w;
    }
    __syncthreads();
#pragma unroll 4
    for (int d = 0; d < 64; ++d) {
      float w = wl[dc + d];
      float2 av = *(const float2*)&As_t[d][ti * 2];
      float2 cv = *(const float2*)&Cs_t[d][tj * 2];
      accv[0][0] += fmaxf(av.x + cv.x, 0.f) * w;
      accv[0][1] += fmaxf(av.x + cv.y, 0.f) * w;
      accv[1][0] += fmaxf(av.y + cv.x, 0.f) * w;
      accv[1][1] += fmaxf(av.y + cv.y, 0.f) * w;
    }
  }

  float* oe = out + 1024;
#pragma unroll
  for (int q = 0; q < 2; ++q) {
    int i = i0 + ti * 2 + q;
    float2 vv;
    vv.x = accv[q][0] + be2;
    vv.y = accv[q][1] + be2;
    *(float2*)&oe[(size_t)(b * 512 + i) * 512 + j0 + tj * 2] = vv;
  }
}

// -------------------------------------------------------------------- launch
extern "C" void kernel_launch(void* const* d_in, const int* in_sizes, int n_in,
                              void* d_out, int out_size, void* d_ws,
                              size_t ws_size, hipStream_t stream) {
  const float* emb  = (const float*)d_in[0];
  const float* W_s1 = (const float*)d_in[1];
  const float* b_s1 = (const float*)d_in[2];
  const float* w_s2 = (const float*)d_in[3];
  const float* b_s2 = (const float*)d_in[4];
  const float* W_e1 = (const float*)d_in[5];
  const float* b_e1 = (const float*)d_in[6];
  const float* w_e2 = (const float*)d_in[7];
  const float* b_e2 = (const float*)d_in[8];
  float* out = (float*)d_out;

  char* ws = (char*)d_ws;
  unsigned short* emb_bf = (unsigned short*)(ws);                  // 2 MB
  unsigned short* Wt_s = (unsigned short*)(ws + 2u * (1u << 20));  // 1 MB
  unsigned short* Wt_e = (unsigned short*)(ws + 3u * (1u << 20));  // 2 MB
  float* A_mat = (float*)(ws + 5u * (1u << 20));                   // 2 MB
  float* C_mat = (float*)(ws + 7u * (1u << 20));                   // 2 MB

  hipLaunchKernelGGL(prep_emb, dim3(512), dim3(256), 0, stream, emb, emb_bf);
  hipLaunchKernelGGL(transpose_cast2, dim3(64, 16, 2), dim3(256), 0, stream,
                     W_s1, W_e1, Wt_s, Wt_e);
  hipLaunchKernelGGL(init_start_out, dim3(1), dim3(256), 0, stream, out, b_s2);
  hipLaunchKernelGGL(gemm_fused, dim3(8, 16, 3), dim3(256), 0, stream,
                     emb_bf, Wt_s, Wt_e, b_s1, w_s2, b_e1, out, A_mat, C_mat);
  hipLaunchKernelGGL(pairwise, dim3(16, 16, 2), dim3(256), 0, stream,
                     A_mat, C_mat, w_e2, b_e2, out);
}

// Round 7
// 123.180 us; speedup vs baseline: 1.2261x; 1.0495x over previous
//
#include <hip/hip_runtime.h>
#include <hip/hip_bf16.h>

// Harness facts (r5/r6): inputs f32, output f32, threshold 2.5e-2 (bf16 cmp).
// dur_us includes ~84us of harness 0xAA-poison fills (2x 268MB @ 41.8us) --
// our controllable budget was ~40us in r6. This round: 3 launches.
//   1. prep (flat grid 2561): emb f32->bf16 | W_s1/W_e1 transpose+cast |
//      out[0:1024]=b_s2, out[1024:]=b_e2
//   2. gemm_fused (16,16,3): 64x32 tiles = 768 blocks (3/CU, no tail)
//      z=0: relu(+b_s1)*w_s2 row-reduce -> atomicAdd out[0:1024]
//      z=1: A_mat = a; z=2: C_mat = c + b_e1
//   3. pairwise (8,16,4): 32i x 64j tile, d split 2-way, d-pair packed f32x2
//      math (v_pk_*), 2x4 micro-tile, atomicAdd partials into out[1024:]

typedef float f32x4 __attribute__((ext_vector_type(4)));
typedef float f32x2 __attribute__((ext_vector_type(2)));
typedef __bf16 bf16x8 __attribute__((ext_vector_type(8)));

static __device__ __forceinline__ unsigned short f2bf(float f) {
  unsigned int u = __builtin_bit_cast(unsigned int, f);
  u += 0x7FFFu + ((u >> 16) & 1u);  // RNE
  return (unsigned short)(u >> 16);
}

// ----------------------------------------------------------------- prep
// blocks 0..511: emb cast; 512..1023: W_s1^T; 1024..2047: W_e1^T;
// 2048: out[0:1024]=b_s2; 2049..2560: out[1024:525312]=b_e2
__global__ __launch_bounds__(256) void prep(
    const float* __restrict__ emb, const float* __restrict__ W_s1,
    const float* __restrict__ W_e1, const float* __restrict__ b_s2,
    const float* __restrict__ b_e2, unsigned short* __restrict__ emb_bf,
    unsigned short* __restrict__ Wt_s, unsigned short* __restrict__ Wt_e,
    float* __restrict__ out) {
  __shared__ float tile[32][33];
  int bx = blockIdx.x, t = threadIdx.x;
  if (bx < 512) {
    int i = bx * 2048 + t * 8;
    f32x4 v0 = *(const f32x4*)&emb[i];
    f32x4 v1 = *(const f32x4*)&emb[i + 4];
    ushort4 o0, o1;
    o0.x = f2bf(v0[0]); o0.y = f2bf(v0[1]);
    o0.z = f2bf(v0[2]); o0.w = f2bf(v0[3]);
    o1.x = f2bf(v1[0]); o1.y = f2bf(v1[1]);
    o1.z = f2bf(v1[2]); o1.w = f2bf(v1[3]);
    *(ushort4*)&emb_bf[i] = o0;
    *(ushort4*)&emb_bf[i + 4] = o1;
  } else if (bx < 2048) {
    const float* in;
    unsigned short* o;
    int R, tid;
    if (bx < 1024) { tid = bx - 512;  in = W_s1; o = Wt_s; R = 1024; }
    else           { tid = bx - 1024; in = W_e1; o = Wt_e; R = 2048; }
    int r0 = (tid >> 4) * 32, c0 = (tid & 15) * 32;
    int a = t >> 3, b4 = t & 7;
    f32x4 v = *(const f32x4*)&in[(size_t)(r0 + a) * 512 + c0 + b4 * 4];
    tile[a][b4 * 4 + 0] = v[0];
    tile[a][b4 * 4 + 1] = v[1];
    tile[a][b4 * 4 + 2] = v[2];
    tile[a][b4 * 4 + 3] = v[3];
    __syncthreads();
    ushort4 o4;
    o4.x = f2bf(tile[b4 * 4 + 0][a]);
    o4.y = f2bf(tile[b4 * 4 + 1][a]);
    o4.z = f2bf(tile[b4 * 4 + 2][a]);
    o4.w = f2bf(tile[b4 * 4 + 3][a]);
    *(ushort4*)&o[(size_t)(c0 + a) * R + r0 + b4 * 4] = o4;
  } else if (bx == 2048) {
    float v = b_s2[0];
    f32x4 o = {v, v, v, v};
    *(f32x4*)&out[t * 4] = o;
  } else {
    float v = b_e2[0];
    f32x4 o = {v, v, v, v};
    *(f32x4*)&out[1024 + (size_t)(bx - 2049) * 1024 + t * 4] = o;
  }
}

// ----------------------------------------------------------------- GEMM
// M=1024, K=1024, N=512 per z. 64m x 32n tile, K-step 64, 4 waves (16m each),
// grid (16,16,3) = 768 blocks = 3/CU exactly.
__global__ __launch_bounds__(256) void gemm_fused(
    const unsigned short* __restrict__ Aemb,   // [1024][1024] bf16
    const unsigned short* __restrict__ Wt_s,   // [512][1024] bf16
    const unsigned short* __restrict__ Wt_e,   // [512][2048] bf16
    const float* __restrict__ b_s1, const float* __restrict__ w_s2,
    const float* __restrict__ b_e1, float* __restrict__ out,
    float* __restrict__ A_mat, float* __restrict__ C_mat) {
  __shared__ unsigned short Al[64][72];
  __shared__ unsigned short Bl[32][72];
  int z = blockIdx.z;
  int n0 = blockIdx.x * 32;
  int m0 = blockIdx.y * 64;
  const unsigned short* Bmat = (z == 0) ? Wt_s : Wt_e;
  int bstride = (z == 0) ? 1024 : 2048;
  int bofs = (z == 2) ? 1024 : 0;

  int t = threadIdx.x, lane = t & 63, wave = t >> 6;
  int wm = wave * 16;
  int lm = lane & 15, g = lane >> 4;

  f32x4 acc[2];
  acc[0] = (f32x4){0.f, 0.f, 0.f, 0.f};
  acc[1] = (f32x4){0.f, 0.f, 0.f, 0.f};

  int ar = t >> 2, ac = (t & 3) * 16;
  int br = t >> 3, bc = (t & 7) * 8;
  for (int k0 = 0; k0 < 1024; k0 += 64) {
    __syncthreads();
    const unsigned short* ap = &Aemb[(size_t)(m0 + ar) * 1024 + k0 + ac];
    *(uint4*)&Al[ar][ac] = *(const uint4*)ap;
    *(uint4*)&Al[ar][ac + 8] = *(const uint4*)(ap + 8);
    *(uint4*)&Bl[br][bc] =
        *(const uint4*)&Bmat[(size_t)(n0 + br) * bstride + bofs + k0 + bc];
    __syncthreads();
#pragma unroll
    for (int kk = 0; kk < 2; ++kk) {
      bf16x8 af = *(const bf16x8*)&Al[wm + lm][kk * 32 + g * 8];
      bf16x8 b0 = *(const bf16x8*)&Bl[lm][kk * 32 + g * 8];
      bf16x8 b1 = *(const bf16x8*)&Bl[16 + lm][kk * 32 + g * 8];
      acc[0] = __builtin_amdgcn_mfma_f32_16x16x32_bf16(af, b0, acc[0], 0, 0, 0);
      acc[1] = __builtin_amdgcn_mfma_f32_16x16x32_bf16(af, b1, acc[1], 0, 0, 0);
    }
  }

  int col0 = n0 + lm, col1 = n0 + 16 + lm;
  if (z == 0) {
    float bs0 = b_s1[col0], bs1 = b_s1[col1];
    float ws0 = w_s2[col0], ws1 = w_s2[col1];
#pragma unroll
    for (int r = 0; r < 4; ++r) {
      float s = fmaxf(acc[0][r] + bs0, 0.f) * ws0 +
                fmaxf(acc[1][r] + bs1, 0.f) * ws1;
      s += __shfl_xor(s, 1);
      s += __shfl_xor(s, 2);
      s += __shfl_xor(s, 4);
      s += __shfl_xor(s, 8);
      if (lm == 0) atomicAdd(&out[m0 + wm + g * 4 + r], s);
    }
  } else {
    float* Out = (z == 1) ? A_mat : C_mat;
    float b0 = (z == 2) ? b_e1[col0] : 0.f;
    float b1 = (z == 2) ? b_e1[col1] : 0.f;
#pragma unroll
    for (int r = 0; r < 4; ++r) {
      int row = m0 + wm + g * 4 + r;
      Out[(size_t)row * 512 + col0] = acc[0][r] + b0;
      Out[(size_t)row * 512 + col1] = acc[1][r] + b1;
    }
  }
}

// ------------------------------------------------------------- pairwise
// end[b,i,j] partial over d-half h: sum_d relu(A[i,d]+C[j,d])*w[d].
// Tile 32i x 64j, 256 thr, micro 2i x 4j, d-pairs packed (f32x2 -> v_pk_*).
// Grid (8,16,4): bz = b*2 + h. atomicAdd into out (pre-inited with b_e2).
__global__ __launch_bounds__(256) void pairwise(
    const float* __restrict__ A_mat, const float* __restrict__ C_mat,
    const float* __restrict__ w_e2, float* __restrict__ out) {
  __shared__ f32x2 As_p[32][32];   // [dp][i]   8 KB
  __shared__ f32x2 Cs_p[32][64];   // [dp][j]  16 KB
  __shared__ f32x2 wlh[128];       // d-half of w_e2, packed
  int t = threadIdx.x;
  int b = blockIdx.z >> 1, h = blockIdx.z & 1;
  int j0 = blockIdx.x * 64, i0 = blockIdx.y * 32;
  int dbase = h * 256;

  if (t < 128) wlh[t] = *(const f32x2*)&w_e2[dbase + 2 * t];

  int ti = t & 15, tj = t >> 4;
  f32x2 acc2[2][4];
#pragma unroll
  for (int q = 0; q < 2; ++q)
#pragma unroll
    for (int r = 0; r < 4; ++r) acc2[q][r] = (f32x2){0.f, 0.f};

  const float* Ab = A_mat + (size_t)(b * 512 + i0) * 512 + dbase;
  const float* Cb = C_mat + (size_t)(b * 512 + j0) * 512 + dbase;
  int si = t & 31, sq = t >> 5;   // A stage: row si, d-octet sq
  int sj = t & 63, s2 = t >> 6;   // C stage: row sj, 16-d group s2
  f32x2 z2 = {0.f, 0.f};

  for (int ch = 0; ch < 4; ++ch) {
    __syncthreads();
    {
      int d0 = sq * 8;
      f32x4 v0 = *(const f32x4*)&Ab[(size_t)si * 512 + ch * 64 + d0];
      f32x4 v1 = *(const f32x4*)&Ab[(size_t)si * 512 + ch * 64 + d0 + 4];
      int dp = d0 >> 1;
      As_p[dp + 0][si] = (f32x2){v0[0], v0[1]};
      As_p[dp + 1][si] = (f32x2){v0[2], v0[3]};
      As_p[dp + 2][si] = (f32x2){v1[0], v1[1]};
      As_p[dp + 3][si] = (f32x2){v1[2], v1[3]};
      int e0 = s2 * 16;
#pragma unroll
      for (int p = 0; p < 4; ++p) {
        f32x4 v = *(const f32x4*)&Cb[(size_t)sj * 512 + ch * 64 + e0 + p * 4];
        int ep = (e0 >> 1) + p * 2;
        Cs_p[ep + 0][sj] = (f32x2){v[0], v[1]};
        Cs_p[ep + 1][sj] = (f32x2){v[2], v[3]};
      }
    }
    __syncthreads();
#pragma unroll 8
    for (int dp = 0; dp < 32; ++dp) {
      f32x2 w2 = wlh[ch * 32 + dp];
      f32x4 av = *(const f32x4*)&As_p[dp][ti * 2];
      f32x4 cv0 = *(const f32x4*)&Cs_p[dp][tj * 4];
      f32x4 cv1 = *(const f32x4*)&Cs_p[dp][tj * 4 + 2];
      f32x2 a0 = {av[0], av[1]}, a1 = {av[2], av[3]};
      f32x2 c0 = {cv0[0], cv0[1]}, c1 = {cv0[2], cv0[3]};
      f32x2 c2 = {cv1[0], cv1[1]}, c3 = {cv1[2], cv1[3]};
      acc2[0][0] += __builtin_elementwise_max(a0 + c0, z2) * w2;
      acc2[0][1] += __builtin_elementwise_max(a0 + c1, z2) * w2;
      acc2[0][2] += __builtin_elementwise_max(a0 + c2, z2) * w2;
      acc2[0][3] += __builtin_elementwise_max(a0 + c3, z2) * w2;
      acc2[1][0] += __builtin_elementwise_max(a1 + c0, z2) * w2;
      acc2[1][1] += __builtin_elementwise_max(a1 + c1, z2) * w2;
      acc2[1][2] += __builtin_elementwise_max(a1 + c2, z2) * w2;
      acc2[1][3] += __builtin_elementwise_max(a1 + c3, z2) * w2;
    }
  }

  float* oe = out + 1024;
#pragma unroll
  for (int q = 0; q < 2; ++q) {
    int i = i0 + ti * 2 + q;
#pragma unroll
    for (int r = 0; r < 4; ++r) {
      float v = acc2[q][r][0] + acc2[q][r][1];
      atomicAdd(&oe[(size_t)(b * 512 + i) * 512 + j0 + tj * 4 + r], v);
    }
  }
}

// -------------------------------------------------------------------- launch
extern "C" void kernel_launch(void* const* d_in, const int* in_sizes, int n_in,
                              void* d_out, int out_size, void* d_ws,
                              size_t ws_size, hipStream_t stream) {
  const float* emb  = (const float*)d_in[0];
  const float* W_s1 = (const float*)d_in[1];
  const float* b_s1 = (const float*)d_in[2];
  const float* w_s2 = (const float*)d_in[3];
  const float* b_s2 = (const float*)d_in[4];
  const float* W_e1 = (const float*)d_in[5];
  const float* b_e1 = (const float*)d_in[6];
  const float* w_e2 = (const float*)d_in[7];
  const float* b_e2 = (const float*)d_in[8];
  float* out = (float*)d_out;

  char* ws = (char*)d_ws;
  unsigned short* emb_bf = (unsigned short*)(ws);                  // 2 MB
  unsigned short* Wt_s = (unsigned short*)(ws + 2u * (1u << 20));  // 1 MB
  unsigned short* Wt_e = (unsigned short*)(ws + 3u * (1u << 20));  // 2 MB
  float* A_mat = (float*)(ws + 5u * (1u << 20));                   // 2 MB
  float* C_mat = (float*)(ws + 7u * (1u << 20));                   // 2 MB

  hipLaunchKernelGGL(prep, dim3(2561), dim3(256), 0, stream,
                     emb, W_s1, W_e1, b_s2, b_e2, emb_bf, Wt_s, Wt_e, out);
  hipLaunchKernelGGL(gemm_fused, dim3(16, 16, 3), dim3(256), 0, stream,
                     emb_bf, Wt_s, Wt_e, b_s1, w_s2, b_e1, out, A_mat, C_mat);
  hipLaunchKernelGGL(pairwise, dim3(8, 16, 4), dim3(256), 0, stream,
                     A_mat, C_mat, w_e2, out);
}

// Round 8
// 118.578 us; speedup vs baseline: 1.2736x; 1.0388x over previous
//
#include <hip/hip_runtime.h>
#include <hip/hip_bf16.h>

// Harness facts: inputs f32, output f32, threshold 2.5e-2 (bf16 cmp).
// dur_us includes ~84us of harness 0xAA poison fills (2x268MB @41.9us) -- fixed.
// r7 post-mortem: d-split pairwise's atomics/extra-init ate the occupancy win.
// This round: pairwise = 512-thr blocks (2 waves/SIMD), full d, plain stores.
//   1. prep (2049 blocks): emb f32->bf16 | W_s1^T, W_e1^T f32->bf16 | out[0:1024]=b_s2
//   2. gemm_fused (16,16,3): 64m x 32n tiles, 768 blocks (3/CU)
//      z=0: relu(+b_s1)*w_s2 row-reduce -> atomicAdd out[0:1024]
//      z=1: A_mat = a; z=2: C_mat = c + b_e1
//   3. pairwise (8,16,2): 32i x 64j tile, 512 thr, 2x2 micro, packed f32x2,
//      be2 added at store (no atomics, no pre-init)

typedef float f32x4 __attribute__((ext_vector_type(4)));
typedef float f32x2 __attribute__((ext_vector_type(2)));
typedef __bf16 bf16x8 __attribute__((ext_vector_type(8)));

static __device__ __forceinline__ unsigned short f2bf(float f) {
  unsigned int u = __builtin_bit_cast(unsigned int, f);
  u += 0x7FFFu + ((u >> 16) & 1u);  // RNE
  return (unsigned short)(u >> 16);
}

// ----------------------------------------------------------------- prep
// 0..511: emb cast; 512..1023: W_s1^T; 1024..2047: W_e1^T; 2048: start init
__global__ __launch_bounds__(256) void prep(
    const float* __restrict__ emb, const float* __restrict__ W_s1,
    const float* __restrict__ W_e1, const float* __restrict__ b_s2,
    unsigned short* __restrict__ emb_bf, unsigned short* __restrict__ Wt_s,
    unsigned short* __restrict__ Wt_e, float* __restrict__ out) {
  __shared__ float tile[32][33];
  int bx = blockIdx.x, t = threadIdx.x;
  if (bx < 512) {
    int i = bx * 2048 + t * 8;
    f32x4 v0 = *(const f32x4*)&emb[i];
    f32x4 v1 = *(const f32x4*)&emb[i + 4];
    ushort4 o0, o1;
    o0.x = f2bf(v0[0]); o0.y = f2bf(v0[1]);
    o0.z = f2bf(v0[2]); o0.w = f2bf(v0[3]);
    o1.x = f2bf(v1[0]); o1.y = f2bf(v1[1]);
    o1.z = f2bf(v1[2]); o1.w = f2bf(v1[3]);
    *(ushort4*)&emb_bf[i] = o0;
    *(ushort4*)&emb_bf[i + 4] = o1;
  } else if (bx < 2048) {
    const float* in;
    unsigned short* o;
    int R, tid;
    if (bx < 1024) { tid = bx - 512;  in = W_s1; o = Wt_s; R = 1024; }
    else           { tid = bx - 1024; in = W_e1; o = Wt_e; R = 2048; }
    int r0 = (tid >> 4) * 32, c0 = (tid & 15) * 32;
    int a = t >> 3, b4 = t & 7;
    f32x4 v = *(const f32x4*)&in[(size_t)(r0 + a) * 512 + c0 + b4 * 4];
    tile[a][b4 * 4 + 0] = v[0];
    tile[a][b4 * 4 + 1] = v[1];
    tile[a][b4 * 4 + 2] = v[2];
    tile[a][b4 * 4 + 3] = v[3];
    __syncthreads();
    ushort4 o4;
    o4.x = f2bf(tile[b4 * 4 + 0][a]);
    o4.y = f2bf(tile[b4 * 4 + 1][a]);
    o4.z = f2bf(tile[b4 * 4 + 2][a]);
    o4.w = f2bf(tile[b4 * 4 + 3][a]);
    *(ushort4*)&o[(size_t)(c0 + a) * R + r0 + b4 * 4] = o4;
  } else {
    float v = b_s2[0];
    f32x4 o = {v, v, v, v};
    *(f32x4*)&out[t * 4] = o;
  }
}

// ----------------------------------------------------------------- GEMM
// M=1024, K=1024, N=512 per z. 64m x 32n tile, K-step 64, 4 waves (16m each),
// grid (16,16,3) = 768 blocks = 3/CU.
__global__ __launch_bounds__(256) void gemm_fused(
    const unsigned short* __restrict__ Aemb,   // [1024][1024] bf16
    const unsigned short* __restrict__ Wt_s,   // [512][1024] bf16
    const unsigned short* __restrict__ Wt_e,   // [512][2048] bf16
    const float* __restrict__ b_s1, const float* __restrict__ w_s2,
    const float* __restrict__ b_e1, float* __restrict__ out,
    float* __restrict__ A_mat, float* __restrict__ C_mat) {
  __shared__ unsigned short Al[64][72];
  __shared__ unsigned short Bl[32][72];
  int z = blockIdx.z;
  int n0 = blockIdx.x * 32;
  int m0 = blockIdx.y * 64;
  const unsigned short* Bmat = (z == 0) ? Wt_s : Wt_e;
  int bstride = (z == 0) ? 1024 : 2048;
  int bofs = (z == 2) ? 1024 : 0;

  int t = threadIdx.x, lane = t & 63, wave = t >> 6;
  int wm = wave * 16;
  int lm = lane & 15, g = lane >> 4;

  f32x4 acc[2];
  acc[0] = (f32x4){0.f, 0.f, 0.f, 0.f};
  acc[1] = (f32x4){0.f, 0.f, 0.f, 0.f};

  int ar = t >> 2, ac = (t & 3) * 16;
  int br = t >> 3, bc = (t & 7) * 8;
  for (int k0 = 0; k0 < 1024; k0 += 64) {
    __syncthreads();
    const unsigned short* ap = &Aemb[(size_t)(m0 + ar) * 1024 + k0 + ac];
    *(uint4*)&Al[ar][ac] = *(const uint4*)ap;
    *(uint4*)&Al[ar][ac + 8] = *(const uint4*)(ap + 8);
    *(uint4*)&Bl[br][bc] =
        *(const uint4*)&Bmat[(size_t)(n0 + br) * bstride + bofs + k0 + bc];
    __syncthreads();
#pragma unroll
    for (int kk = 0; kk < 2; ++kk) {
      bf16x8 af = *(const bf16x8*)&Al[wm + lm][kk * 32 + g * 8];
      bf16x8 b0 = *(const bf16x8*)&Bl[lm][kk * 32 + g * 8];
      bf16x8 b1 = *(const bf16x8*)&Bl[16 + lm][kk * 32 + g * 8];
      acc[0] = __builtin_amdgcn_mfma_f32_16x16x32_bf16(af, b0, acc[0], 0, 0, 0);
      acc[1] = __builtin_amdgcn_mfma_f32_16x16x32_bf16(af, b1, acc[1], 0, 0, 0);
    }
  }

  int col0 = n0 + lm, col1 = n0 + 16 + lm;
  if (z == 0) {
    float bs0 = b_s1[col0], bs1 = b_s1[col1];
    float ws0 = w_s2[col0], ws1 = w_s2[col1];
#pragma unroll
    for (int r = 0; r < 4; ++r) {
      float s = fmaxf(acc[0][r] + bs0, 0.f) * ws0 +
                fmaxf(acc[1][r] + bs1, 0.f) * ws1;
      s += __shfl_xor(s, 1);
      s += __shfl_xor(s, 2);
      s += __shfl_xor(s, 4);
      s += __shfl_xor(s, 8);
      if (lm == 0) atomicAdd(&out[m0 + wm + g * 4 + r], s);
    }
  } else {
    float* Out = (z == 1) ? A_mat : C_mat;
    float b0 = (z == 2) ? b_e1[col0] : 0.f;
    float b1 = (z == 2) ? b_e1[col1] : 0.f;
#pragma unroll
    for (int r = 0; r < 4; ++r) {
      int row = m0 + wm + g * 4 + r;
      Out[(size_t)row * 512 + col0] = acc[0][r] + b0;
      Out[(size_t)row * 512 + col1] = acc[1][r] + b1;
    }
  }
}

// ------------------------------------------------------------- pairwise
// end[b,i,j] = sum_d relu(A[i,d]+C[j,d])*w[d] + b_e2, full d per block.
// 512 thr (8 waves = 2/SIMD at 1 block/CU), grid (8,16,2) = 256 blocks.
// Micro 2i x 2j; d-pairs packed f32x2 (v_pk_*); plain contiguous stores.
__global__ __launch_bounds__(512) void pairwise(
    const float* __restrict__ A_mat, const float* __restrict__ C_mat,
    const float* __restrict__ w_e2, const float* __restrict__ b_e2,
    float* __restrict__ out) {
  __shared__ f32x2 As_p[32][32];   // [dp][i]   8 KB (per 64-d chunk)
  __shared__ f32x2 Cs_p[32][64];   // [dp][j]  16 KB
  __shared__ f32x2 wl2[256];       // w_e2 packed, all 512 d
  int t = threadIdx.x;
  int b = blockIdx.z;
  int j0 = blockIdx.x * 64, i0 = blockIdx.y * 32;

  if (t < 256) wl2[t] = *(const f32x2*)&w_e2[2 * t];
  float be2 = b_e2[0];

  int ti = t >> 5, tj = t & 31;  // 16 i-groups x2, 32 j-groups x2
  f32x2 acc2[2][2];
#pragma unroll
  for (int q = 0; q < 2; ++q)
#pragma unroll
    for (int r = 0; r < 2; ++r) acc2[q][r] = (f32x2){0.f, 0.f};

  const float* Ab = A_mat + (size_t)(b * 512 + i0) * 512;
  const float* Cb = C_mat + (size_t)(b * 512 + j0) * 512;
  int si = t & 31, sq = t >> 5;  // A stage: row si, d-quad sq (0..15)
  int sj = t & 63, s2 = t >> 6;  // C stage: row sj, d-oct  s2 (0..7)
  f32x2 z2 = {0.f, 0.f};

  for (int ch = 0; ch < 8; ++ch) {
    __syncthreads();
    {
      f32x4 va = *(const f32x4*)&Ab[(size_t)si * 512 + ch * 64 + sq * 4];
      As_p[sq * 2 + 0][si] = (f32x2){va[0], va[1]};
      As_p[sq * 2 + 1][si] = (f32x2){va[2], va[3]};
      f32x4 v0 = *(const f32x4*)&Cb[(size_t)sj * 512 + ch * 64 + s2 * 8];
      f32x4 v1 = *(const f32x4*)&Cb[(size_t)sj * 512 + ch * 64 + s2 * 8 + 4];
      Cs_p[s2 * 4 + 0][sj] = (f32x2){v0[0], v0[1]};
      Cs_p[s2 * 4 + 1][sj] = (f32x2){v0[2], v0[3]};
      Cs_p[s2 * 4 + 2][sj] = (f32x2){v1[0], v1[1]};
      Cs_p[s2 * 4 + 3][sj] = (f32x2){v1[2], v1[3]};
    }
    __syncthreads();
#pragma unroll 8
    for (int dp = 0; dp < 32; ++dp) {
      f32x2 w2 = wl2[ch * 32 + dp];
      f32x4 av = *(const f32x4*)&As_p[dp][ti * 2];
      f32x4 cv = *(const f32x4*)&Cs_p[dp][tj * 2];
      f32x2 a0 = {av[0], av[1]}, a1 = {av[2], av[3]};
      f32x2 c0 = {cv[0], cv[1]}, c1 = {cv[2], cv[3]};
      acc2[0][0] += __builtin_elementwise_max(a0 + c0, z2) * w2;
      acc2[0][1] += __builtin_elementwise_max(a0 + c1, z2) * w2;
      acc2[1][0] += __builtin_elementwise_max(a1 + c0, z2) * w2;
      acc2[1][1] += __builtin_elementwise_max(a1 + c1, z2) * w2;
    }
  }

  float* oe = out + 1024;
#pragma unroll
  for (int q = 0; q < 2; ++q) {
    int i = i0 + ti * 2 + q;
    float2 vv;
    vv.x = acc2[q][0][0] + acc2[q][0][1] + be2;
    vv.y = acc2[q][1][0] + acc2[q][1][1] + be2;
    *(float2*)&oe[(size_t)(b * 512 + i) * 512 + j0 + tj * 2] = vv;
  }
}

// -------------------------------------------------------------------- launch
extern "C" void kernel_launch(void* const* d_in, const int* in_sizes, int n_in,
                              void* d_out, int out_size, void* d_ws,
                              size_t ws_size, hipStream_t stream) {
  const float* emb  = (const float*)d_in[0];
  const float* W_s1 = (const float*)d_in[1];
  const float* b_s1 = (const float*)d_in[2];
  const float* w_s2 = (const float*)d_in[3];
  const float* b_s2 = (const float*)d_in[4];
  const float* W_e1 = (const float*)d_in[5];
  const float* b_e1 = (const float*)d_in[6];
  const float* w_e2 = (const float*)d_in[7];
  const float* b_e2 = (const float*)d_in[8];
  float* out = (float*)d_out;

  char* ws = (char*)d_ws;
  unsigned short* emb_bf = (unsigned short*)(ws);                  // 2 MB
  unsigned short* Wt_s = (unsigned short*)(ws + 2u * (1u << 20));  // 1 MB
  unsigned short* Wt_e = (unsigned short*)(ws + 3u * (1u << 20));  // 2 MB
  float* A_mat = (float*)(ws + 5u * (1u << 20));                   // 2 MB
  float* C_mat = (float*)(ws + 7u * (1u << 20));                   // 2 MB

  hipLaunchKernelGGL(prep, dim3(2049), dim3(256), 0, stream,
                     emb, W_s1, W_e1, b_s2, emb_bf, Wt_s, Wt_e, out);
  hipLaunchKernelGGL(gemm_fused, dim3(16, 16, 3), dim3(256), 0, stream,
                     emb_bf, Wt_s, Wt_e, b_s1, w_s2, b_e1, out, A_mat, C_mat);
  hipLaunchKernelGGL(pairwise, dim3(8, 16, 2), dim3(512), 0, stream,
                     A_mat, C_mat, w_e2, b_e2, out);
}